// Round 3
// baseline (243.962 us; speedup 1.0000x reference)
//
#include <hip/hip_runtime.h>
#include <hip/hip_fp16.h>

#define HH 128
#define WW 128
#define CIN 128
#define COUT 256
#define K9 9
#define HW (HH*WW)          // 16384
#define PIX (2*HW)          // 32768
#define KDIM (CIN*K9)       // 1152
#define BN_EPS 1e-5f

typedef __attribute__((ext_vector_type(8))) short short8;
typedef __attribute__((ext_vector_type(4))) short short4v;
typedef __attribute__((ext_vector_type(4))) float f32x4;

// 16B sampling metadata: 4 clamped hw-indices (u16) + 4 premultiplied bilinear
// weights (f16, mask & validity folded in). Layout: meta[k][pixel].
struct Meta16 { ushort4 idx; __half2 w01, w23; };
static_assert(sizeof(Meta16) == 16, "");

__device__ __forceinline__ unsigned short f2bf(float f) {
    union { float f; unsigned u; } x; x.f = f;
    unsigned r = x.u + 0x7FFFu + ((x.u >> 16) & 1u);
    return (unsigned short)(r >> 16);
}

// ---------------------------------------------------------------------------
// prep_w: wT[o][e'] = bf16(w_dcn[o][c][k]), e' = k*128 + c  (k-major K order)
// ---------------------------------------------------------------------------
__global__ __launch_bounds__(128) void prep_w(const float* __restrict__ w_dcn,
                                              unsigned short* __restrict__ wT) {
    const int c = threadIdx.x;
    const int k = blockIdx.x;
    const int o = blockIdx.y;
    wT[(size_t)o*KDIM + k*CIN + c] = f2bf(w_dcn[(size_t)o*KDIM + c*K9 + k]);
}

// ---------------------------------------------------------------------------
// offs_kernel: per (pixel, k) compute dy (ch 2k), dx (ch 2k+1), mask (ch 18+k)
// of the 3x3 SAME conv -> compressed bilinear metadata.
// grid (128, 9). XCD-swizzled bx so each XCD works a contiguous 4096-px strip
// (x rows stay L2-resident); all 9 k-blocks of a strip land on the same XCD
// (linear id = by*128+bx, id%8 == bx%8).
// ---------------------------------------------------------------------------
__global__ __launch_bounds__(256) void offs_kernel(
    const float* __restrict__ x, const float* __restrict__ w_off,
    const float* __restrict__ b_off, Meta16* __restrict__ meta)
{
    const int bx = (blockIdx.x & 7) * 16 + (blockIdx.x >> 3);   // bijective, 128%8==0
    const int pg = bx * 256 + threadIdx.x;
    const int k  = blockIdx.y;
    const int b  = pg >> 14;
    const int hw = pg & 16383;
    const int h  = hw >> 7;
    const int w  = hw & 127;

    const float* __restrict__ wdy = w_off + (2*k)   * KDIM;
    const float* __restrict__ wdx = w_off + (2*k+1) * KDIM;
    const float* __restrict__ wm  = w_off + (18+k)  * KDIM;

    float dy = b_off[2*k], dx = b_off[2*k+1], mm = b_off[18+k];

    const float* __restrict__ xb = x + (size_t)b * (CIN*HW);
    for (int c = 0; c < CIN; ++c) {
        const float* __restrict__ xc = xb + c * HW;
        const int wbase = c * 9;
        #pragma unroll
        for (int kh = 0; kh < 3; ++kh) {
            const int yy = h + kh - 1;
            const bool yok = ((unsigned)yy < HH);
            const int rowoff = yy * WW;
            #pragma unroll
            for (int kw = 0; kw < 3; ++kw) {
                const int xx = w + kw - 1;
                float v = (yok && ((unsigned)xx < WW)) ? xc[rowoff + xx] : 0.f;
                const int wi = wbase + kh*3 + kw;
                dy = fmaf(v, wdy[wi], dy);
                dx = fmaf(v, wdx[wi], dx);
                mm = fmaf(v, wm[wi],  mm);
            }
        }
    }

    const float ky = (float)(k / 3) - 1.0f;
    const float kx = (float)(k % 3) - 1.0f;
    const float py = (float)h + ky + dy;
    const float px = (float)w + kx + dx;
    const float msk = 1.0f / (1.0f + expf(-mm));

    const float y0f = floorf(py);
    const float x0f = floorf(px);
    const float wy = py - y0f;
    const float wx = px - x0f;
    const int y0 = (int)y0f, x0 = (int)x0f;
    const int y1 = y0 + 1,   x1 = x0 + 1;

    const bool v00 = ((unsigned)y0 < HH) && ((unsigned)x0 < WW);
    const bool v01 = ((unsigned)y0 < HH) && ((unsigned)x1 < WW);
    const bool v10 = ((unsigned)y1 < HH) && ((unsigned)x0 < WW);
    const bool v11 = ((unsigned)y1 < HH) && ((unsigned)x1 < WW);

    const int y0c = min(max(y0, 0), HH-1), y1c = min(max(y1, 0), HH-1);
    const int x0c = min(max(x0, 0), WW-1), x1c = min(max(x1, 0), WW-1);

    Meta16 m;
    m.idx.x = (unsigned short)(y0c * WW + x0c);
    m.idx.y = (unsigned short)(y0c * WW + x1c);
    m.idx.z = (unsigned short)(y1c * WW + x0c);
    m.idx.w = (unsigned short)(y1c * WW + x1c);
    const float f00 = v00 ? (1.f-wy)*(1.f-wx)*msk : 0.f;
    const float f01 = v01 ? (1.f-wy)*wx*msk       : 0.f;
    const float f10 = v10 ? wy*(1.f-wx)*msk       : 0.f;
    const float f11 = v11 ? wy*wx*msk             : 0.f;
    m.w01 = __floats2half2_rn(f00, f01);
    m.w23 = __floats2half2_rn(f10, f11);
    meta[(size_t)k * PIX + pg] = m;   // [k][pixel]: coalesced write & read
}

// ---------------------------------------------------------------------------
// dcn_mfma: implicit GEMM via mfma_f32_16x16x32_bf16.
//   M = 256 outputs (A = wT from global/L2), N = 32 pixels (B = gathered vals
//   staged bf16 in LDS), K = 1152 in e' = k*128+c order.
// 256 threads = 4 waves (wave wv owns o in [64wv,64wv+64)).
// grid = 1024 blocks (32 px each) -> 4 blocks/CU for latency hiding;
// XCD-swizzled so each XCD owns a contiguous 4096-px strip (L2-resident).
// ---------------------------------------------------------------------------
__global__ __launch_bounds__(256) void dcn_mfma(
    const float* __restrict__ x, const Meta16* __restrict__ meta,
    const unsigned short* __restrict__ wT,
    const float* __restrict__ b_dcn, const float* __restrict__ gamma,
    const float* __restrict__ beta, const float* __restrict__ mmean,
    const float* __restrict__ mvar, float* __restrict__ out)
{
    __shared__ __align__(16) unsigned short Vs[32*40];   // [p][kk], stride 40

    const int t   = threadIdx.x;
    const int l   = t & 63;
    const int wv  = t >> 6;
    const int l15 = l & 15;
    const int lq  = l >> 4;

    const int bid = (blockIdx.x & 7) * 128 + (blockIdx.x >> 3);  // 1024%8==0
    const int pg0 = bid * 32;
    const int b   = pg0 >> 14;
    const int hw0 = pg0 & 16383;
    const float* __restrict__ xb = x + (size_t)b * (CIN*HW);

    f32x4 acc[4][2];
    #pragma unroll
    for (int m = 0; m < 4; ++m)
        #pragma unroll
        for (int n = 0; n < 2; ++n) acc[m][n] = (f32x4){0.f,0.f,0.f,0.f};

    const int p  = t & 31;   // gather: pixel
    const int cg = t >> 5;   // gather: 4-channel group 0..7

    for (int tt = 0; tt < 36; ++tt) {
        const int k  = tt >> 2;
        const int c0 = (tt & 3) * 32;

        __syncthreads();

        // A-frags (weights) from global (L2-resident dense lines)
        short8 a[4];
        #pragma unroll
        for (int m = 0; m < 4; ++m) {
            const int o = wv*64 + m*16 + l15;
            a[m] = *(const short8*)(wT + (size_t)o*KDIM + tt*32 + lq*8);
        }

        // gather 4 vals (one meta, 4 consecutive c) -> bf16 -> LDS
        {
            const Meta16 mt = meta[(size_t)k * PIX + pg0 + p];
            const float w0 = __low2float(mt.w01), w1 = __high2float(mt.w01);
            const float w2 = __low2float(mt.w23), w3 = __high2float(mt.w23);
            const int i0 = mt.idx.x, i1 = mt.idx.y, i2 = mt.idx.z, i3 = mt.idx.w;
            short4v pk;
            #pragma unroll
            for (int j = 0; j < 4; ++j) {
                const float* __restrict__ xc = xb + (size_t)(c0 + cg*4 + j) * HW;
                const float v = w0*xc[i0] + w1*xc[i1] + w2*xc[i2] + w3*xc[i3];
                pk[j] = (short)f2bf(v);
            }
            *(short4v*)&Vs[p*40 + cg*4] = pk;
        }

        __syncthreads();

        // B-frags from LDS + 8 MFMA
        #pragma unroll
        for (int n = 0; n < 2; ++n) {
            const short8 bf = *(const short8*)&Vs[(n*16 + l15)*40 + lq*8];
            #pragma unroll
            for (int m = 0; m < 4; ++m)
                acc[m][n] = __builtin_amdgcn_mfma_f32_16x16x32_bf16(
                                a[m], bf, acc[m][n], 0, 0, 0);
        }
    }

    // epilogue: BN + ReLU, coalesced stores
    #pragma unroll
    for (int m = 0; m < 4; ++m) {
        #pragma unroll
        for (int r = 0; r < 4; ++r) {
            const int o = wv*64 + m*16 + lq*4 + r;
            const float sc = gamma[o] * rsqrtf(mvar[o] + BN_EPS);
            const float sh = (b_dcn[o] - mmean[o]) * sc + beta[o];
            float* __restrict__ op = out + ((size_t)(b*COUT + o) << 14) + hw0;
            #pragma unroll
            for (int n = 0; n < 2; ++n) {
                const float v = fmaf(acc[m][n][r], sc, sh);
                op[n*16 + l15] = fmaxf(v, 0.f);
            }
        }
    }
}

extern "C" void kernel_launch(void* const* d_in, const int* in_sizes, int n_in,
                              void* d_out, int out_size, void* d_ws, size_t ws_size,
                              hipStream_t stream) {
    (void)in_sizes; (void)n_in; (void)out_size; (void)ws_size;
    const float* x      = (const float*)d_in[0];
    const float* w_off  = (const float*)d_in[1];
    const float* b_off  = (const float*)d_in[2];
    const float* w_dcn  = (const float*)d_in[3];
    const float* b_dcn  = (const float*)d_in[4];
    const float* gamma  = (const float*)d_in[5];
    const float* beta   = (const float*)d_in[6];
    const float* mmean  = (const float*)d_in[7];
    const float* mvar   = (const float*)d_in[8];
    float* out = (float*)d_out;

    unsigned short* wT = (unsigned short*)d_ws;                  // 589824 B
    Meta16* meta = (Meta16*)((char*)d_ws + (size_t)COUT*KDIM*2); // 4.72 MB

    prep_w<<<dim3(9, 256), 128, 0, stream>>>(w_dcn, wT);
    offs_kernel<<<dim3(PIX/256, K9), 256, 0, stream>>>(x, w_off, b_off, meta);
    dcn_mfma<<<dim3(PIX/32), 256, 0, stream>>>(x, meta, wT, b_dcn,
                                               gamma, beta, mmean, mvar, out);
}

// Round 4
// 114.775 us; speedup vs baseline: 2.1256x; 2.1256x over previous
//
#include <hip/hip_runtime.h>
#include <hip/hip_fp16.h>

#define HH 128
#define WW 128
#define CIN 128
#define COUT 256
#define K9 9
#define HW (HH*WW)          // 16384
#define PIX (2*HW)          // 32768
#define KDIM (CIN*K9)       // 1152
#define BN_EPS 1e-5f

typedef __attribute__((ext_vector_type(8))) short short8;
typedef __attribute__((ext_vector_type(4))) float f32x4;
typedef unsigned short u16;

// 16B sampling metadata: 4 clamped hw-indices (u16) + 4 premultiplied bilinear
// weights (f16, mask & validity folded in). Layout: meta[k][pixel].
struct __align__(16) Meta16 { ushort4 idx; __half2 w01, w23; };
static_assert(sizeof(Meta16) == 16, "");

__device__ __forceinline__ u16 f2bf(float f) {
    union { float f; unsigned u; } x; x.f = f;
    unsigned r = x.u + 0x7FFFu + ((x.u >> 16) & 1u);
    return (u16)(r >> 16);
}
__device__ __forceinline__ float bf2f(u16 u) {
    union { unsigned u; float f; } x; x.u = ((unsigned)u) << 16; return x.f;
}

// weighted 4-corner combine of 8-channel bf16 slices -> bf16x8
__device__ __forceinline__ short8 combine4(const short8* cv, float w0, float w1,
                                           float w2, float w3) {
    short8 r;
    #pragma unroll
    for (int j = 0; j < 8; ++j) {
        float v = w0*bf2f((u16)cv[0][j]) + w1*bf2f((u16)cv[1][j])
                + w2*bf2f((u16)cv[2][j]) + w3*bf2f((u16)cv[3][j]);
        r[j] = (short)f2bf(v);
    }
    return r;
}

// ---------------------------------------------------------------------------
// prep_xt: x [B][C][HW] f32  ->  xt [B][HW][C] bf16 (NHWC). LDS transpose.
// ---------------------------------------------------------------------------
__global__ __launch_bounds__(256) void prep_xt(const float* __restrict__ x,
                                               u16* __restrict__ xt) {
    __shared__ float tile[32][129];
    const int b   = blockIdx.y;
    const int hw0 = blockIdx.x * 32;
    const float* __restrict__ xb = x + (size_t)b * (CIN*HW);
    #pragma unroll
    for (int i = 0; i < 16; ++i) {
        const int idx = threadIdx.x + i*256;
        const int c = idx >> 5, hwl = idx & 31;
        tile[hwl][c] = xb[(size_t)c*HW + hw0 + hwl];
    }
    __syncthreads();
    const int hwl = threadIdx.x >> 3;
    const int c0  = (threadIdx.x & 7) * 16;
    short8 s0, s1;
    #pragma unroll
    for (int j = 0; j < 8; ++j) {
        s0[j] = (short)f2bf(tile[hwl][c0 + j]);
        s1[j] = (short)f2bf(tile[hwl][c0 + 8 + j]);
    }
    u16* dst = xt + ((size_t)b*HW + hw0 + hwl)*CIN + c0;
    *(short8*)dst = s0;
    *(short8*)(dst + 8) = s1;
}

// ---------------------------------------------------------------------------
// prep_w: wT[o][e'] = bf16(w_dcn[o][c][k]), e' = k*128 + c (k-major)
// ---------------------------------------------------------------------------
__global__ __launch_bounds__(128) void prep_w(const float* __restrict__ w_dcn,
                                              u16* __restrict__ wT) {
    const int c = threadIdx.x, k = blockIdx.x, o = blockIdx.y;
    wT[(size_t)o*KDIM + k*CIN + c] = f2bf(w_dcn[(size_t)o*KDIM + c*K9 + k]);
}

// prep_woff: wOffT[j][k*128+c] = bf16(w_off[j][c][k]) for j<27, 0 for j=27..31
__global__ __launch_bounds__(128) void prep_woff(const float* __restrict__ w_off,
                                                 u16* __restrict__ wOffT) {
    const int c = threadIdx.x, k = blockIdx.x, j = blockIdx.y;
    wOffT[(size_t)j*KDIM + k*CIN + c] =
        (j < 27) ? f2bf(w_off[(size_t)j*KDIM + c*K9 + k]) : (u16)0;
}

// ---------------------------------------------------------------------------
// offs_mfma: weight_info[27][pix] = conv3x3(x) via MFMA (M=32 padded), fused
// with the meta (offset/mask -> bilinear metadata) epilogue.
// Block: 256 thr = 4 waves; wave wv owns 16 pixels. B-gather = dense NHWC
// 16B loads, no interpolation, no LDS in main loop, no barriers.
// ---------------------------------------------------------------------------
__global__ __launch_bounds__(256) void offs_mfma(
    const u16* __restrict__ xt, const u16* __restrict__ wOffT,
    const float* __restrict__ b_off, Meta16* __restrict__ meta)
{
    __shared__ float wiL[4][32][17];
    const int t = threadIdx.x, l = t & 63, wv = t >> 6;
    const int l15 = l & 15, lq = l >> 4;
    const int bid = (blockIdx.x & 7) * 64 + (blockIdx.x >> 3);  // 512 blocks
    const int pg0 = bid * 64;
    const int b   = pg0 >> 14;
    const int pg  = pg0 + wv*16 + l15;     // this lane's pixel (B col)
    const int hw  = pg & 16383;
    const int h   = hw >> 7, w = hw & 127;
    const u16* __restrict__ xtb = xt + (size_t)b * (HW*CIN);

    f32x4 acc[2];
    acc[0] = (f32x4){0.f,0.f,0.f,0.f};
    acc[1] = (f32x4){0.f,0.f,0.f,0.f};
    const short8 Z = {0,0,0,0,0,0,0,0};

    #pragma unroll
    for (int tt = 0; tt < 36; ++tt) {
        const int k  = tt >> 2, c0 = (tt & 3) * 32;
        const int yy = h + (k/3) - 1;
        const int xx = w + (k%3) - 1;
        const bool valid = ((unsigned)yy < HH) && ((unsigned)xx < WW);
        const int idx = min(max(yy,0),HH-1)*WW + min(max(xx,0),WW-1);
        short8 bv = *(const short8*)(xtb + (size_t)idx*CIN + c0 + lq*8);
        short8 a0 = *(const short8*)(wOffT + (size_t)l15*KDIM      + tt*32 + lq*8);
        short8 a1 = *(const short8*)(wOffT + (size_t)(16+l15)*KDIM + tt*32 + lq*8);
        if (!valid) bv = Z;
        acc[0] = __builtin_amdgcn_mfma_f32_16x16x32_bf16(a0, bv, acc[0], 0,0,0);
        acc[1] = __builtin_amdgcn_mfma_f32_16x16x32_bf16(a1, bv, acc[1], 0,0,0);
    }

    // scatter acc (C layout: col=lane&15 -> pixel, row=(lane>>4)*4+r) to LDS
    #pragma unroll
    for (int m = 0; m < 2; ++m)
        #pragma unroll
        for (int r = 0; r < 4; ++r)
            wiL[wv][m*16 + lq*4 + r][l15] = acc[m][r];
    __syncthreads();

    // per (pixel, k): build Meta16. lanes: pixel=l15, k = lq + 4*kk
    #pragma unroll
    for (int kk = 0; kk < 3; ++kk) {
        const int k = lq + kk*4;
        if (k < 9) {
            const float dy = wiL[wv][2*k  ][l15] + b_off[2*k];
            const float dx = wiL[wv][2*k+1][l15] + b_off[2*k+1];
            const float mm = wiL[wv][18+k ][l15] + b_off[18+k];
            const float py = (float)h + (float)(k/3) - 1.0f + dy;
            const float px = (float)w + (float)(k%3) - 1.0f + dx;
            const float msk = 1.0f / (1.0f + expf(-mm));
            const float y0f = floorf(py), x0f = floorf(px);
            const float wy = py - y0f, wx = px - x0f;
            const int y0 = (int)y0f, x0 = (int)x0f;
            const int y1 = y0 + 1,   x1 = x0 + 1;
            const bool v00 = ((unsigned)y0 < HH) && ((unsigned)x0 < WW);
            const bool v01 = ((unsigned)y0 < HH) && ((unsigned)x1 < WW);
            const bool v10 = ((unsigned)y1 < HH) && ((unsigned)x0 < WW);
            const bool v11 = ((unsigned)y1 < HH) && ((unsigned)x1 < WW);
            const int y0c = min(max(y0,0),HH-1), y1c = min(max(y1,0),HH-1);
            const int x0c = min(max(x0,0),WW-1), x1c = min(max(x1,0),WW-1);
            Meta16 mo;
            mo.idx.x = (u16)(y0c*WW + x0c);
            mo.idx.y = (u16)(y0c*WW + x1c);
            mo.idx.z = (u16)(y1c*WW + x0c);
            mo.idx.w = (u16)(y1c*WW + x1c);
            const float f00 = v00 ? (1.f-wy)*(1.f-wx)*msk : 0.f;
            const float f01 = v01 ? (1.f-wy)*wx*msk       : 0.f;
            const float f10 = v10 ? wy*(1.f-wx)*msk       : 0.f;
            const float f11 = v11 ? wy*wx*msk             : 0.f;
            mo.w01 = __floats2half2_rn(f00, f01);
            mo.w23 = __floats2half2_rn(f10, f11);
            meta[(size_t)k*PIX + pg] = mo;
        }
    }
}

// ---------------------------------------------------------------------------
// dcn_mfma: implicit GEMM via mfma_f32_16x16x32_bf16, NHWC dense gather.
//   M = 256 outputs (A = wT, L2), N = 64 pixels (B = bilinear vals, bf16 LDS,
//   double-buffered), K = 1152 k-major. Depth-2 pipeline: corners for tile
//   t+2 issued during tile t's MFMAs; meta prefetched one k (4 tiles) ahead.
// ---------------------------------------------------------------------------
__global__ __launch_bounds__(256) void dcn_mfma(
    const u16* __restrict__ xt, const Meta16* __restrict__ meta,
    const u16* __restrict__ wT, const float* __restrict__ b_dcn,
    const float* __restrict__ gamma, const float* __restrict__ beta,
    const float* __restrict__ mmean, const float* __restrict__ mvar,
    float* __restrict__ out)
{
    __shared__ __align__(16) u16 Vs[2][64*40];   // [buf][p][kk] stride 40

    const int t = threadIdx.x, l = t & 63, wv = t >> 6;
    const int l15 = l & 15, lq = l >> 4;
    const int bid = (blockIdx.x & 7) * 64 + (blockIdx.x >> 3);  // 512 blocks
    const int pg0 = bid * 64;
    const int b   = pg0 >> 14;
    const int hw0 = pg0 & 16383;
    const u16* __restrict__ xtb = xt + (size_t)b * (HW*CIN);

    const int p  = t & 63;          // gather pixel (block-local)
    const int cb = (t >> 6) * 8;    // gather channel sub-slot (8 ch)
    const int pp = pg0 + p;

    f32x4 acc[4][4];
    #pragma unroll
    for (int m = 0; m < 4; ++m)
        #pragma unroll
        for (int n = 0; n < 4; ++n) acc[m][n] = (f32x4){0.f,0.f,0.f,0.f};

#define CLD(dst, mt, c0) do { \
    dst[0] = *(const short8*)(xtb + (size_t)(mt).idx.x*CIN + (c0) + cb); \
    dst[1] = *(const short8*)(xtb + (size_t)(mt).idx.y*CIN + (c0) + cb); \
    dst[2] = *(const short8*)(xtb + (size_t)(mt).idx.z*CIN + (c0) + cb); \
    dst[3] = *(const short8*)(xtb + (size_t)(mt).idx.w*CIN + (c0) + cb); \
} while (0)

    short8 cv[2][4];
    Meta16 mtC = meta[pp];                       // k = 0
    // prologue: tile0 -> Vs[0]; tile1 corners in flight
    CLD(cv[0], mtC, 0);
    {
        const float u0 = __low2float(mtC.w01), u1 = __high2float(mtC.w01);
        const float u2 = __low2float(mtC.w23), u3 = __high2float(mtC.w23);
        *(short8*)&Vs[0][p*40 + cb] = combine4(cv[0], u0, u1, u2, u3);
    }
    CLD(cv[1], mtC, 32);
    __syncthreads();

    for (int kk = 0; kk < 9; ++kk) {
        Meta16 mtN;
        if (kk < 8) mtN = meta[(size_t)(kk+1)*PIX + pp];
        #pragma unroll
        for (int s = 0; s < 4; ++s) {
            const int tt  = kk*4 + s;
            const int cur = s & 1;               // tile tt lives in Vs[tt&1]

            // A-frags for tile tt (issued first -> counted vmcnt waits)
            short8 a[4];
            #pragma unroll
            for (int m = 0; m < 4; ++m)
                a[m] = *(const short8*)(wT + (size_t)(wv*64 + m*16 + l15)*KDIM
                                           + tt*32 + lq*8);

            // issue corners for tile tt+2 into cv[cur]
            if (tt + 2 <= 35) {
                if (s < 2) { CLD(cv[cur], mtC, ((tt+2)&3)*32); }
                else       { CLD(cv[cur], mtN, ((tt+2)&3)*32); }
            }

            // MFMAs for tile tt
            #pragma unroll
            for (int n = 0; n < 4; ++n) {
                const short8 bf = *(const short8*)&Vs[cur][(n*16 + l15)*40 + lq*8];
                #pragma unroll
                for (int m = 0; m < 4; ++m)
                    acc[m][n] = __builtin_amdgcn_mfma_f32_16x16x32_bf16(
                                    a[m], bf, acc[m][n], 0, 0, 0);
            }

            // combine tile tt+1 (corners issued last iter) -> Vs[cur^1]
            if (tt + 1 <= 35) {
                const Meta16 mw = (s < 3) ? mtC : mtN;
                const float u0 = __low2float(mw.w01), u1 = __high2float(mw.w01);
                const float u2 = __low2float(mw.w23), u3 = __high2float(mw.w23);
                *(short8*)&Vs[cur^1][p*40 + cb] =
                    combine4(cv[cur^1], u0, u1, u2, u3);
            }
            __syncthreads();
        }
        mtC = mtN;
    }
#undef CLD

    // epilogue: bias + BN + ReLU, coalesced stores
    #pragma unroll
    for (int m = 0; m < 4; ++m) {
        #pragma unroll
        for (int r = 0; r < 4; ++r) {
            const int o = wv*64 + m*16 + lq*4 + r;
            const float sc = gamma[o] * rsqrtf(mvar[o] + BN_EPS);
            const float sh = (b_dcn[o] - mmean[o]) * sc + beta[o];
            float* __restrict__ op = out + ((size_t)(b*COUT + o) << 14) + hw0;
            #pragma unroll
            for (int n = 0; n < 4; ++n) {
                const float v = fmaf(acc[m][n][r], sc, sh);
                op[n*16 + l15] = fmaxf(v, 0.f);
            }
        }
    }
}

extern "C" void kernel_launch(void* const* d_in, const int* in_sizes, int n_in,
                              void* d_out, int out_size, void* d_ws, size_t ws_size,
                              hipStream_t stream) {
    (void)in_sizes; (void)n_in; (void)out_size; (void)ws_size;
    const float* x      = (const float*)d_in[0];
    const float* w_off  = (const float*)d_in[1];
    const float* b_off  = (const float*)d_in[2];
    const float* w_dcn  = (const float*)d_in[3];
    const float* b_dcn  = (const float*)d_in[4];
    const float* gamma  = (const float*)d_in[5];
    const float* beta   = (const float*)d_in[6];
    const float* mmean  = (const float*)d_in[7];
    const float* mvar   = (const float*)d_in[8];
    float* out = (float*)d_out;

    char* ws = (char*)d_ws;
    u16*    xtp   = (u16*)ws;                                   // 8,388,608 B
    u16*    wT    = (u16*)(ws + 8388608);                       //   589,824 B
    u16*    wOffT = (u16*)(ws + 8388608 + 589824);              //    73,728 B
    Meta16* meta  = (Meta16*)(ws + 8388608 + 589824 + 73728);   // 4,718,592 B

    prep_xt  <<<dim3(HW/32, 2), 256, 0, stream>>>(x, xtp);
    prep_w   <<<dim3(9, 256), 128, 0, stream>>>(w_dcn, wT);
    prep_woff<<<dim3(9, 32),  128, 0, stream>>>(w_off, wOffT);
    offs_mfma<<<dim3(PIX/64), 256, 0, stream>>>(xtp, wOffT, b_off, meta);
    dcn_mfma <<<dim3(PIX/64), 256, 0, stream>>>(xtp, meta, wT, b_dcn,
                                                gamma, beta, mmean, mvar, out);
}

// Round 5
// 113.550 us; speedup vs baseline: 2.1485x; 1.0108x over previous
//
#include <hip/hip_runtime.h>
#include <hip/hip_fp16.h>

#define HH 128
#define WW 128
#define CIN 128
#define COUT 256
#define K9 9
#define HW (HH*WW)          // 16384
#define PIX (2*HW)          // 32768
#define KDIM (CIN*K9)       // 1152
#define BN_EPS 1e-5f

typedef __attribute__((ext_vector_type(8))) short short8;
typedef __attribute__((ext_vector_type(4))) float f32x4;
typedef unsigned short u16;
typedef unsigned int u32;

// 16B sampling metadata: 4 clamped hw-indices (u16) + 4 premultiplied bilinear
// weights (f16, mask & validity folded in). Layout: meta[k][pixel].
struct __align__(16) Meta16 { ushort4 idx; __half2 w01, w23; };
static_assert(sizeof(Meta16) == 16, "");

__device__ __forceinline__ u16 f2bf(float f) {
    union { float f; u32 u; } x; x.f = f;
    u32 r = x.u + 0x7FFFu + ((x.u >> 16) & 1u);
    return (u16)(r >> 16);
}
__device__ __forceinline__ float bflo(u32 d) {
    union { u32 u; float f; } x; x.u = d << 16; return x.f;
}
__device__ __forceinline__ float bfhi(u32 d) {
    union { u32 u; float f; } x; x.u = d & 0xFFFF0000u; return x.f;
}
__device__ __forceinline__ u32 pack2bf(float lo, float hi) {
    union { float f; u32 u; } a, b; a.f = lo; b.f = hi;
    u32 rl = a.u + 0x7FFFu + ((a.u >> 16) & 1u);
    u32 rh = b.u + 0x7FFFu + ((b.u >> 16) & 1u);
    return (rl >> 16) | (rh & 0xFFFF0000u);
}

// weighted 4-corner combine of one 8-channel bf16 slice (u32-pair unpack)
__device__ __forceinline__ short8 combine8(short8 c0, short8 c1, short8 c2,
                                           short8 c3, float w0, float w1,
                                           float w2, float w3) {
    union U { short8 s; u32 d[4]; };
    U a, b, c, e, r;
    a.s = c0; b.s = c1; c.s = c2; e.s = c3;
    #pragma unroll
    for (int i = 0; i < 4; ++i) {
        float lo = w0*bflo(a.d[i]) + w1*bflo(b.d[i])
                 + w2*bflo(c.d[i]) + w3*bflo(e.d[i]);
        float hi = w0*bfhi(a.d[i]) + w1*bfhi(b.d[i])
                 + w2*bfhi(c.d[i]) + w3*bfhi(e.d[i]);
        r.d[i] = pack2bf(lo, hi);
    }
    return r.s;
}

// ---------------------------------------------------------------------------
// prep_xt: x [B][C][HW] f32  ->  xt [B][HW][C] bf16 (NHWC). LDS transpose.
// ---------------------------------------------------------------------------
__global__ __launch_bounds__(256) void prep_xt(const float* __restrict__ x,
                                               u16* __restrict__ xt) {
    __shared__ float tile[32][129];
    const int b   = blockIdx.y;
    const int hw0 = blockIdx.x * 32;
    const float* __restrict__ xb = x + (size_t)b * (CIN*HW);
    #pragma unroll
    for (int i = 0; i < 16; ++i) {
        const int idx = threadIdx.x + i*256;
        const int c = idx >> 5, hwl = idx & 31;
        tile[hwl][c] = xb[(size_t)c*HW + hw0 + hwl];
    }
    __syncthreads();
    const int hwl = threadIdx.x >> 3;
    const int c0  = (threadIdx.x & 7) * 16;
    short8 s0, s1;
    #pragma unroll
    for (int j = 0; j < 8; ++j) {
        s0[j] = (short)f2bf(tile[hwl][c0 + j]);
        s1[j] = (short)f2bf(tile[hwl][c0 + 8 + j]);
    }
    u16* dst = xt + ((size_t)b*HW + hw0 + hwl)*CIN + c0;
    *(short8*)dst = s0;
    *(short8*)(dst + 8) = s1;
}

// ---------------------------------------------------------------------------
// prep_w: wT[o][e'] = bf16(w_dcn[o][c][k]), e' = k*128 + c (k-major)
// ---------------------------------------------------------------------------
__global__ __launch_bounds__(128) void prep_w(const float* __restrict__ w_dcn,
                                              u16* __restrict__ wT) {
    const int c = threadIdx.x, k = blockIdx.x, o = blockIdx.y;
    wT[(size_t)o*KDIM + k*CIN + c] = f2bf(w_dcn[(size_t)o*KDIM + c*K9 + k]);
}

// prep_woff: wOffT[j][k*128+c] = bf16(w_off[j][c][k]) for j<27, 0 for j=27..31
__global__ __launch_bounds__(128) void prep_woff(const float* __restrict__ w_off,
                                                 u16* __restrict__ wOffT) {
    const int c = threadIdx.x, k = blockIdx.x, j = blockIdx.y;
    wOffT[(size_t)j*KDIM + k*CIN + c] =
        (j < 27) ? f2bf(w_off[(size_t)j*KDIM + c*K9 + k]) : (u16)0;
}

// ---------------------------------------------------------------------------
// offs_mfma: weight_info[27][pix] = conv3x3(x) via MFMA (M=32 padded), fused
// with the meta (offset/mask -> bilinear metadata) epilogue. (unchanged R4)
// ---------------------------------------------------------------------------
__global__ __launch_bounds__(256) void offs_mfma(
    const u16* __restrict__ xt, const u16* __restrict__ wOffT,
    const float* __restrict__ b_off, Meta16* __restrict__ meta)
{
    __shared__ float wiL[4][32][17];
    const int t = threadIdx.x, l = t & 63, wv = t >> 6;
    const int l15 = l & 15, lq = l >> 4;
    const int bid = (blockIdx.x & 7) * 64 + (blockIdx.x >> 3);  // 512 blocks
    const int pg0 = bid * 64;
    const int b   = pg0 >> 14;
    const int pg  = pg0 + wv*16 + l15;
    const int hw  = pg & 16383;
    const int h   = hw >> 7, w = hw & 127;
    const u16* __restrict__ xtb = xt + (size_t)b * (HW*CIN);

    f32x4 acc[2];
    acc[0] = (f32x4){0.f,0.f,0.f,0.f};
    acc[1] = (f32x4){0.f,0.f,0.f,0.f};
    const short8 Z = {0,0,0,0,0,0,0,0};

    #pragma unroll
    for (int tt = 0; tt < 36; ++tt) {
        const int k  = tt >> 2, c0 = (tt & 3) * 32;
        const int yy = h + (k/3) - 1;
        const int xx = w + (k%3) - 1;
        const bool valid = ((unsigned)yy < HH) && ((unsigned)xx < WW);
        const int idx = min(max(yy,0),HH-1)*WW + min(max(xx,0),WW-1);
        short8 bv = *(const short8*)(xtb + (size_t)idx*CIN + c0 + lq*8);
        short8 a0 = *(const short8*)(wOffT + (size_t)l15*KDIM      + tt*32 + lq*8);
        short8 a1 = *(const short8*)(wOffT + (size_t)(16+l15)*KDIM + tt*32 + lq*8);
        if (!valid) bv = Z;
        acc[0] = __builtin_amdgcn_mfma_f32_16x16x32_bf16(a0, bv, acc[0], 0,0,0);
        acc[1] = __builtin_amdgcn_mfma_f32_16x16x32_bf16(a1, bv, acc[1], 0,0,0);
    }

    #pragma unroll
    for (int m = 0; m < 2; ++m)
        #pragma unroll
        for (int r = 0; r < 4; ++r)
            wiL[wv][m*16 + lq*4 + r][l15] = acc[m][r];
    __syncthreads();

    #pragma unroll
    for (int kk = 0; kk < 3; ++kk) {
        const int k = lq + kk*4;
        if (k < 9) {
            const float dy = wiL[wv][2*k  ][l15] + b_off[2*k];
            const float dx = wiL[wv][2*k+1][l15] + b_off[2*k+1];
            const float mm = wiL[wv][18+k ][l15] + b_off[18+k];
            const float py = (float)h + (float)(k/3) - 1.0f + dy;
            const float px = (float)w + (float)(k%3) - 1.0f + dx;
            const float msk = 1.0f / (1.0f + expf(-mm));
            const float y0f = floorf(py), x0f = floorf(px);
            const float wy = py - y0f, wx = px - x0f;
            const int y0 = (int)y0f, x0 = (int)x0f;
            const int y1 = y0 + 1,   x1 = x0 + 1;
            const bool v00 = ((unsigned)y0 < HH) && ((unsigned)x0 < WW);
            const bool v01 = ((unsigned)y0 < HH) && ((unsigned)x1 < WW);
            const bool v10 = ((unsigned)y1 < HH) && ((unsigned)x0 < WW);
            const bool v11 = ((unsigned)y1 < HH) && ((unsigned)x1 < WW);
            const int y0c = min(max(y0,0),HH-1), y1c = min(max(y1,0),HH-1);
            const int x0c = min(max(x0,0),WW-1), x1c = min(max(x1,0),WW-1);
            Meta16 mo;
            mo.idx.x = (u16)(y0c*WW + x0c);
            mo.idx.y = (u16)(y0c*WW + x1c);
            mo.idx.z = (u16)(y1c*WW + x0c);
            mo.idx.w = (u16)(y1c*WW + x1c);
            const float f00 = v00 ? (1.f-wy)*(1.f-wx)*msk : 0.f;
            const float f01 = v01 ? (1.f-wy)*wx*msk       : 0.f;
            const float f10 = v10 ? wy*(1.f-wx)*msk       : 0.f;
            const float f11 = v11 ? wy*wx*msk             : 0.f;
            mo.w01 = __floats2half2_rn(f00, f01);
            mo.w23 = __floats2half2_rn(f10, f11);
            meta[(size_t)k*PIX + pg] = mo;
        }
    }
}

// ---------------------------------------------------------------------------
// dcn_mfma: implicit GEMM, per-k slab pipeline (ONE barrier per k):
//   phase k: [MFMA 64/wave over Vs[cur] (A prefetched 1 sub-tile ahead)]
//            [combine corners(k+1) -> Vs[cur^1]]  (corners issued phase k-1)
//            [issue corners k+2 + meta k+3]
//            [lgkmcnt(0); raw s_barrier]          (vmcnt stays counted)
// Gather: thread owns (pixel p, 32 consecutive ch) -> each 64B xt line fully
// consumed by ONE thread. LDS [p][128ch] with granule-XOR cs^=(p&7): both
// ds_write_b128 and ds_read_b128 at the 8-cyc floor.
// ---------------------------------------------------------------------------
__global__ __launch_bounds__(256, 2) void dcn_mfma(
    const u16* __restrict__ xt, const Meta16* __restrict__ meta,
    const u16* __restrict__ wT, const float* __restrict__ b_dcn,
    const float* __restrict__ gamma, const float* __restrict__ beta,
    const float* __restrict__ mmean, const float* __restrict__ mvar,
    float* __restrict__ out)
{
    __shared__ __align__(16) u16 Vs[2][64*128];   // 32 KB

    const int t = threadIdx.x, l = t & 63, wv = t >> 6;
    const int l15 = l & 15, lq = l >> 4;
    const int bid = (blockIdx.x & 7) * 64 + (blockIdx.x >> 3);  // 512 blocks
    const int pg0 = bid * 64;
    const int b   = pg0 >> 14;
    const int hw0 = pg0 & 16383;
    const u16* __restrict__ xtb = xt + (size_t)b * (HW*CIN);

    const int p  = t & 63;          // gather pixel (block-local)
    const int cq = t >> 6;          // channel quarter (32 ch)
    const int pp = pg0 + p;

    f32x4 acc[4][4];
    #pragma unroll
    for (int m = 0; m < 4; ++m)
        #pragma unroll
        for (int n = 0; n < 4; ++n) acc[m][n] = (f32x4){0.f,0.f,0.f,0.f};

    short8 crn[4][4];   // [corner][8ch-slice]

#define CLD4(mt) do { \
    const u16* b0_ = xtb + (size_t)(mt).idx.x*CIN + cq*32; \
    const u16* b1_ = xtb + (size_t)(mt).idx.y*CIN + cq*32; \
    const u16* b2_ = xtb + (size_t)(mt).idx.z*CIN + cq*32; \
    const u16* b3_ = xtb + (size_t)(mt).idx.w*CIN + cq*32; \
    _Pragma("unroll") \
    for (int j_ = 0; j_ < 4; ++j_) { \
        crn[0][j_] = *(const short8*)(b0_ + j_*8); \
        crn[1][j_] = *(const short8*)(b1_ + j_*8); \
        crn[2][j_] = *(const short8*)(b2_ + j_*8); \
        crn[3][j_] = *(const short8*)(b3_ + j_*8); } \
} while (0)

#define COMBINE_TO(buf, mt) do { \
    const float u0_ = __low2float((mt).w01), u1_ = __high2float((mt).w01); \
    const float u2_ = __low2float((mt).w23), u3_ = __high2float((mt).w23); \
    _Pragma("unroll") \
    for (int j_ = 0; j_ < 4; ++j_) { \
        short8 vj_ = combine8(crn[0][j_], crn[1][j_], crn[2][j_], crn[3][j_], \
                              u0_, u1_, u2_, u3_); \
        *(short8*)&Vs[buf][p*128 + (((cq*4 + j_) ^ (p & 7)) * 8)] = vj_; } \
} while (0)

    // ---- prologue ----
    Meta16 mtA = meta[pp];                     // k=0
    CLD4(mtA);
    Meta16 mtB = meta[(size_t)1*PIX + pp];     // k=1
    COMBINE_TO(0, mtA);                        // vals k=0 -> Vs[0]
    CLD4(mtB);                                 // corners k=1 in flight
    Meta16 mtC = meta[(size_t)2*PIX + pp];     // k=2
    asm volatile("s_waitcnt lgkmcnt(0)" ::: "memory");
    __builtin_amdgcn_s_barrier();

    int cur = 0;
    for (int k = 0; k < 9; ++k) {
        // ---- MFMA phase over Vs[cur] (vals k); A prefetched 1 sub-tile ahead
        short8 a[4][4];   // [s][m] -- SSA-renamed, ~2 live at a time
        #pragma unroll
        for (int m = 0; m < 4; ++m)
            a[0][m] = *(const short8*)(wT + (size_t)(wv*64 + m*16 + l15)*KDIM
                                          + (k*4 + 0)*32 + lq*8);
        #pragma unroll
        for (int s = 0; s < 4; ++s) {
            if (s < 3) {
                #pragma unroll
                for (int m = 0; m < 4; ++m)
                    a[s+1][m] = *(const short8*)(wT
                        + (size_t)(wv*64 + m*16 + l15)*KDIM
                        + (k*4 + s + 1)*32 + lq*8);
            }
            #pragma unroll
            for (int n = 0; n < 4; ++n) {
                const int row = n*16 + l15;
                const short8 bf = *(const short8*)
                    &Vs[cur][row*128 + (((s*4 + lq) ^ (row & 7)) * 8)];
                #pragma unroll
                for (int m = 0; m < 4; ++m)
                    acc[m][n] = __builtin_amdgcn_mfma_f32_16x16x32_bf16(
                                    a[s][m], bf, acc[m][n], 0, 0, 0);
            }
        }

        // ---- combine k+1 (corners issued last phase) -> Vs[cur^1]
        if (k < 8) COMBINE_TO(cur ^ 1, mtB);

        // ---- issue corners k+2, roll meta
        if (k < 7) {
            CLD4(mtC);
            mtB = mtC;
            if (k < 6) mtC = meta[(size_t)(k + 3)*PIX + pp];
        }

        asm volatile("s_waitcnt lgkmcnt(0)" ::: "memory");
        __builtin_amdgcn_s_barrier();
        cur ^= 1;
    }
#undef CLD4
#undef COMBINE_TO

    // ---- epilogue: bias + BN + ReLU, coalesced stores ----
    #pragma unroll
    for (int m = 0; m < 4; ++m) {
        #pragma unroll
        for (int r = 0; r < 4; ++r) {
            const int o = wv*64 + m*16 + lq*4 + r;
            const float sc = gamma[o] * rsqrtf(mvar[o] + BN_EPS);
            const float sh = (b_dcn[o] - mmean[o]) * sc + beta[o];
            float* __restrict__ op = out + ((size_t)(b*COUT + o) << 14) + hw0;
            #pragma unroll
            for (int n = 0; n < 4; ++n) {
                const float v = fmaf(acc[m][n][r], sc, sh);
                op[n*16 + l15] = fmaxf(v, 0.f);
            }
        }
    }
}

extern "C" void kernel_launch(void* const* d_in, const int* in_sizes, int n_in,
                              void* d_out, int out_size, void* d_ws, size_t ws_size,
                              hipStream_t stream) {
    (void)in_sizes; (void)n_in; (void)out_size; (void)ws_size;
    const float* x      = (const float*)d_in[0];
    const float* w_off  = (const float*)d_in[1];
    const float* b_off  = (const float*)d_in[2];
    const float* w_dcn  = (const float*)d_in[3];
    const float* b_dcn  = (const float*)d_in[4];
    const float* gamma  = (const float*)d_in[5];
    const float* beta   = (const float*)d_in[6];
    const float* mmean  = (const float*)d_in[7];
    const float* mvar   = (const float*)d_in[8];
    float* out = (float*)d_out;

    char* ws = (char*)d_ws;
    u16*    xtp   = (u16*)ws;                                   // 8,388,608 B
    u16*    wT    = (u16*)(ws + 8388608);                       //   589,824 B
    u16*    wOffT = (u16*)(ws + 8388608 + 589824);              //    73,728 B
    Meta16* meta  = (Meta16*)(ws + 8388608 + 589824 + 73728);   // 4,718,592 B

    prep_xt  <<<dim3(HW/32, 2), 256, 0, stream>>>(x, xtp);
    prep_w   <<<dim3(9, 256), 128, 0, stream>>>(w_dcn, wT);
    prep_woff<<<dim3(9, 32),  128, 0, stream>>>(w_off, wOffT);
    offs_mfma<<<dim3(PIX/64), 256, 0, stream>>>(xtp, wOffT, b_off, meta);
    dcn_mfma <<<dim3(PIX/64), 256, 0, stream>>>(xtp, meta, wT, b_dcn,
                                                gamma, beta, mmean, mvar, out);
}

// Round 6
// 94.710 us; speedup vs baseline: 2.5759x; 1.1989x over previous
//
#include <hip/hip_runtime.h>
#include <hip/hip_fp16.h>

#define HH 128
#define WW 128
#define CIN 128
#define COUT 256
#define K9 9
#define HW (HH*WW)          // 16384
#define PIX (2*HW)          // 32768
#define KDIM (CIN*K9)       // 1152
#define BN_EPS 1e-5f

typedef __attribute__((ext_vector_type(8))) short short8;
typedef __attribute__((ext_vector_type(4))) float f32x4;
typedef unsigned short u16;
typedef unsigned int u32;

// 16B sampling metadata: 4 clamped hw-indices (u16) + 4 premultiplied bilinear
// weights (f16, mask & validity folded in). Lives in LDS only.
struct __align__(16) Meta16 { ushort4 idx; __half2 w01, w23; };
static_assert(sizeof(Meta16) == 16, "");

__device__ __forceinline__ u16 f2bf(float f) {
    union { float f; u32 u; } x; x.f = f;
    u32 r = x.u + 0x7FFFu + ((x.u >> 16) & 1u);
    return (u16)(r >> 16);
}
__device__ __forceinline__ float bflo(u32 d) {
    union { u32 u; float f; } x; x.u = d << 16; return x.f;
}
__device__ __forceinline__ float bfhi(u32 d) {
    union { u32 u; float f; } x; x.u = d & 0xFFFF0000u; return x.f;
}
__device__ __forceinline__ u32 pack2bf(float lo, float hi) {
    union { float f; u32 u; } a, b; a.f = lo; b.f = hi;
    u32 rl = a.u + 0x7FFFu + ((a.u >> 16) & 1u);
    u32 rh = b.u + 0x7FFFu + ((b.u >> 16) & 1u);
    return (rl >> 16) | (rh & 0xFFFF0000u);
}

// weighted 4-corner combine of one 8-channel bf16 slice
__device__ __forceinline__ short8 combine8(short8 c0, short8 c1, short8 c2,
                                           short8 c3, float w0, float w1,
                                           float w2, float w3) {
    union U { short8 s; u32 d[4]; };
    U a, b, c, e, r;
    a.s = c0; b.s = c1; c.s = c2; e.s = c3;
    #pragma unroll
    for (int i = 0; i < 4; ++i) {
        float lo = w0*bflo(a.d[i]) + w1*bflo(b.d[i])
                 + w2*bflo(c.d[i]) + w3*bflo(e.d[i]);
        float hi = w0*bfhi(a.d[i]) + w1*bfhi(b.d[i])
                 + w2*bfhi(c.d[i]) + w3*bfhi(e.d[i]);
        r.d[i] = pack2bf(lo, hi);
    }
    return r.s;
}

// ---------------------------------------------------------------------------
// prep_xt: x [B][C][HW] f32  ->  xt [B][HW][C] bf16 (NHWC). LDS transpose.
// ---------------------------------------------------------------------------
__global__ __launch_bounds__(256) void prep_xt(const float* __restrict__ x,
                                               u16* __restrict__ xt) {
    __shared__ float tile[32][129];
    const int b   = blockIdx.y;
    const int hw0 = blockIdx.x * 32;
    const float* __restrict__ xb = x + (size_t)b * (CIN*HW);
    #pragma unroll
    for (int i = 0; i < 16; ++i) {
        const int idx = threadIdx.x + i*256;
        const int c = idx >> 5, hwl = idx & 31;
        tile[hwl][c] = xb[(size_t)c*HW + hw0 + hwl];
    }
    __syncthreads();
    const int hwl = threadIdx.x >> 3;
    const int c0  = (threadIdx.x & 7) * 16;
    short8 s0, s1;
    #pragma unroll
    for (int j = 0; j < 8; ++j) {
        s0[j] = (short)f2bf(tile[hwl][c0 + j]);
        s1[j] = (short)f2bf(tile[hwl][c0 + 8 + j]);
    }
    u16* dst = xt + ((size_t)b*HW + hw0 + hwl)*CIN + c0;
    *(short8*)dst = s0;
    *(short8*)(dst + 8) = s1;
}

// ---------------------------------------------------------------------------
// prep_wall: k-major bf16 transposes of w_dcn (o<256) and w_off (o>=256).
// ---------------------------------------------------------------------------
__global__ __launch_bounds__(128) void prep_wall(const float* __restrict__ w_dcn,
                                                 const float* __restrict__ w_off,
                                                 u16* __restrict__ wT,
                                                 u16* __restrict__ wOffT) {
    const int c = threadIdx.x, k = blockIdx.x, o = blockIdx.y;
    if (o < COUT) {
        wT[(size_t)o*KDIM + k*CIN + c] = f2bf(w_dcn[(size_t)o*KDIM + c*K9 + k]);
    } else {
        const int j = o - COUT;
        wOffT[(size_t)j*KDIM + k*CIN + c] =
            (j < 27) ? f2bf(w_off[(size_t)j*KDIM + c*K9 + k]) : (u16)0;
    }
}

// ---------------------------------------------------------------------------
// dcn_fused: offs-conv (MFMA, meta->LDS) + implicit-GEMM DCN + BN + ReLU.
// Per block: 64 pixels, 256 thr = 4 waves, M=256 outs, K=1152 (k-major).
// Gather: ONE instruction per pixel (lane = corner*16 + chunk), via
// global_load_lds into Vraw (raw corners, half-tile of 32 px), then an
// LDS->LDS combine8 produces the bf16 B-tile Vs (XOR-swizzled chunks).
// ---------------------------------------------------------------------------
__global__ __launch_bounds__(256, 2) void dcn_fused(
    const u16* __restrict__ xt, const u16* __restrict__ wT,
    const u16* __restrict__ wOffT, const float* __restrict__ b_off,
    const float* __restrict__ b_dcn, const float* __restrict__ gamma,
    const float* __restrict__ beta, const float* __restrict__ mmean,
    const float* __restrict__ mvar, float* __restrict__ out)
{
    __shared__ __align__(16) Meta16 metaL[K9*64];    //  9216 B
    __shared__ __align__(16) u16 Vraw[32*512];       // 32768 B (32 px raw)
    __shared__ __align__(16) u16 Vs[2][64*128];      // 32768 B
    float* wiL = (float*)&Vs[0][0];                  // alias (offs phase only)

    const int t = threadIdx.x, l = t & 63, wv = t >> 6;
    const int l15 = l & 15, lq = l >> 4;
    const int bid = (blockIdx.x & 7) * 64 + (blockIdx.x >> 3);  // 512 blocks
    const int pg0 = bid * 64;
    const int b   = pg0 >> 14;
    const int hw0 = pg0 & 16383;
    const u16* __restrict__ xtb = xt + (size_t)b * (HW*CIN);

    // ================= phase -1: offsets conv + meta build =================
    {
        const int pg = pg0 + wv*16 + l15;
        const int hw = pg & 16383;
        const int h = hw >> 7, w = hw & 127;
        f32x4 oa0 = {0.f,0.f,0.f,0.f}, oa1 = {0.f,0.f,0.f,0.f};
        const short8 Z = {0,0,0,0,0,0,0,0};
        #pragma unroll
        for (int tt = 0; tt < 36; ++tt) {
            const int k = tt >> 2, c0 = (tt & 3) * 32;
            const int yy = h + (k/3) - 1, xx = w + (k%3) - 1;
            const bool valid = ((unsigned)yy < HH) && ((unsigned)xx < WW);
            const int idx = min(max(yy,0),HH-1)*WW + min(max(xx,0),WW-1);
            short8 bv = *(const short8*)(xtb + (size_t)idx*CIN + c0 + lq*8);
            short8 a0 = *(const short8*)(wOffT + (size_t)l15*KDIM      + tt*32 + lq*8);
            short8 a1 = *(const short8*)(wOffT + (size_t)(16+l15)*KDIM + tt*32 + lq*8);
            if (!valid) bv = Z;
            oa0 = __builtin_amdgcn_mfma_f32_16x16x32_bf16(a0, bv, oa0, 0,0,0);
            oa1 = __builtin_amdgcn_mfma_f32_16x16x32_bf16(a1, bv, oa1, 0,0,0);
        }
        #pragma unroll
        for (int r = 0; r < 4; ++r) {
            wiL[(wv*32 + lq*4 + r)*17 + l15]      = oa0[r];
            wiL[(wv*32 + 16 + lq*4 + r)*17 + l15] = oa1[r];
        }
        __syncthreads();
        #pragma unroll
        for (int kk = 0; kk < 3; ++kk) {
            const int k = lq + kk*4;
            if (k < 9) {
                const float dy = wiL[(wv*32 + 2*k  )*17 + l15] + b_off[2*k];
                const float dx = wiL[(wv*32 + 2*k+1)*17 + l15] + b_off[2*k+1];
                const float mm = wiL[(wv*32 + 18+k )*17 + l15] + b_off[18+k];
                const float py = (float)h + (float)(k/3) - 1.0f + dy;
                const float px = (float)w + (float)(k%3) - 1.0f + dx;
                const float msk = 1.0f / (1.0f + expf(-mm));
                const float y0f = floorf(py), x0f = floorf(px);
                const float wy = py - y0f, wx = px - x0f;
                const int y0 = (int)y0f, x0 = (int)x0f;
                const int y1 = y0 + 1,   x1 = x0 + 1;
                const bool v00 = ((unsigned)y0 < HH) && ((unsigned)x0 < WW);
                const bool v01 = ((unsigned)y0 < HH) && ((unsigned)x1 < WW);
                const bool v10 = ((unsigned)y1 < HH) && ((unsigned)x0 < WW);
                const bool v11 = ((unsigned)y1 < HH) && ((unsigned)x1 < WW);
                const int y0c = min(max(y0,0),HH-1), y1c = min(max(y1,0),HH-1);
                const int x0c = min(max(x0,0),WW-1), x1c = min(max(x1,0),WW-1);
                Meta16 mo;
                mo.idx.x = (u16)(y0c*WW + x0c);
                mo.idx.y = (u16)(y0c*WW + x1c);
                mo.idx.z = (u16)(y1c*WW + x0c);
                mo.idx.w = (u16)(y1c*WW + x1c);
                const float f00 = v00 ? (1.f-wy)*(1.f-wx)*msk : 0.f;
                const float f01 = v01 ? (1.f-wy)*wx*msk       : 0.f;
                const float f10 = v10 ? wy*(1.f-wx)*msk       : 0.f;
                const float f11 = v11 ? wy*wx*msk             : 0.f;
                mo.w01 = __floats2half2_rn(f00, f01);
                mo.w23 = __floats2half2_rn(f10, f11);
                metaL[k*64 + wv*16 + l15] = mo;
            }
        }
        __syncthreads();   // metaL ready; wiL (Vs alias) dead
    }

    // ================= main GEMM =================
    const int gc  = l >> 4;    // gather corner 0..3
    const int gch = l & 15;    // gather 16B chunk 0..15

// one instruction per pixel: 64 lanes = 4 corners x 16 chunks -> Vraw linear
#define GATHER(k_, h_) do { \
    u16 idxr_[8]; \
    _Pragma("unroll") \
    for (int i_ = 0; i_ < 8; ++i_) { \
        const int px_ = (h_)*32 + wv*8 + i_; \
        idxr_[i_] = ((const u16*)&metaL[(k_)*64 + px_])[gc]; \
    } \
    _Pragma("unroll") \
    for (int i_ = 0; i_ < 8; ++i_) { \
        const u16* src_ = xtb + (size_t)idxr_[i_]*CIN + gch*8; \
        __builtin_amdgcn_global_load_lds(src_, &Vraw[(wv*8 + i_)*512], 16, 0, 0); \
    } \
} while (0)

// LDS->LDS: weighted 4-corner combine, 2x 8-ch units per thread
#define COMBINE(k_, h_, buf_) do { \
    const int pxl_ = t >> 3; \
    const int px_  = (h_)*32 + pxl_; \
    const Meta16 mw_ = metaL[(k_)*64 + px_]; \
    const float u0_ = __low2float(mw_.w01), u1_ = __high2float(mw_.w01); \
    const float u2_ = __low2float(mw_.w23), u3_ = __high2float(mw_.w23); \
    _Pragma("unroll") \
    for (int u_ = 0; u_ < 2; ++u_) { \
        const int ch_ = (t & 7) + u_*8; \
        const short8 c0_ = *(const short8*)&Vraw[pxl_*512 + 0*128 + ch_*8]; \
        const short8 c1_ = *(const short8*)&Vraw[pxl_*512 + 1*128 + ch_*8]; \
        const short8 c2_ = *(const short8*)&Vraw[pxl_*512 + 2*128 + ch_*8]; \
        const short8 c3_ = *(const short8*)&Vraw[pxl_*512 + 3*128 + ch_*8]; \
        short8 v_ = combine8(c0_, c1_, c2_, c3_, u0_, u1_, u2_, u3_); \
        *(short8*)&Vs[buf_][px_*128 + ((ch_ ^ (px_ & 7)))*8] = v_; \
    } \
} while (0)

    f32x4 acc[4][4];
    #pragma unroll
    for (int m = 0; m < 4; ++m)
        #pragma unroll
        for (int n = 0; n < 4; ++n) acc[m][n] = (f32x4){0.f,0.f,0.f,0.f};

    // prologue
    GATHER(0, 0);
    __syncthreads();          // vmcnt(0): h0 landed
    COMBINE(0, 0, 0);
    __syncthreads();          // Vraw consumable
    GATHER(0, 1);
    __syncthreads();          // h1 landed
    COMBINE(0, 1, 0);
    __syncthreads();          // Vs[0] complete
    GATHER(1, 0);             // in flight across MFMA(0)

    int cur = 0;
    for (int k = 0; k < 9; ++k) {
        // ---- MFMA over Vs[cur], A prefetched 1 sub-tile ahead ----
        short8 a[4][4];
        #pragma unroll
        for (int m = 0; m < 4; ++m)
            a[0][m] = *(const short8*)(wT + (size_t)(wv*64 + m*16 + l15)*KDIM
                                          + (k*4 + 0)*32 + lq*8);
        #pragma unroll
        for (int s = 0; s < 4; ++s) {
            if (s < 3) {
                #pragma unroll
                for (int m = 0; m < 4; ++m)
                    a[s+1][m] = *(const short8*)(wT
                        + (size_t)(wv*64 + m*16 + l15)*KDIM
                        + (k*4 + s + 1)*32 + lq*8);
            }
            #pragma unroll
            for (int n = 0; n < 4; ++n) {
                const int row = n*16 + l15;
                const short8 bf = *(const short8*)
                    &Vs[cur][row*128 + (((s*4 + lq) ^ (row & 7)) * 8)];
                #pragma unroll
                for (int m = 0; m < 4; ++m)
                    acc[m][n] = __builtin_amdgcn_mfma_f32_16x16x32_bf16(
                                    a[s][m], bf, acc[m][n], 0, 0, 0);
            }
        }

        __syncthreads();      // vmcnt(0): gather(k+1,h0) landed; Vs[cur] reads done
        if (k < 8) {
            COMBINE(k+1, 0, cur ^ 1);
            __syncthreads();  // Vraw consumable
            GATHER(k+1, 1);
            __syncthreads();  // vmcnt(0): h1 landed
            COMBINE(k+1, 1, cur ^ 1);
            __syncthreads();  // Vs[cur^1] complete, Vraw consumable
            if (k < 7) GATHER(k + 2, 0);   // in flight across next MFMA
        }
        cur ^= 1;
    }
#undef GATHER
#undef COMBINE

    // ---- epilogue: bias + BN + ReLU, coalesced stores ----
    #pragma unroll
    for (int m = 0; m < 4; ++m) {
        #pragma unroll
        for (int r = 0; r < 4; ++r) {
            const int o = wv*64 + m*16 + lq*4 + r;
            const float sc = gamma[o] * rsqrtf(mvar[o] + BN_EPS);
            const float sh = (b_dcn[o] - mmean[o]) * sc + beta[o];
            float* __restrict__ op = out + ((size_t)(b*COUT + o) << 14) + hw0;
            #pragma unroll
            for (int n = 0; n < 4; ++n) {
                const float v = fmaf(acc[m][n][r], sc, sh);
                op[n*16 + l15] = fmaxf(v, 0.f);
            }
        }
    }
}

extern "C" void kernel_launch(void* const* d_in, const int* in_sizes, int n_in,
                              void* d_out, int out_size, void* d_ws, size_t ws_size,
                              hipStream_t stream) {
    (void)in_sizes; (void)n_in; (void)out_size; (void)ws_size;
    const float* x      = (const float*)d_in[0];
    const float* w_off  = (const float*)d_in[1];
    const float* b_off  = (const float*)d_in[2];
    const float* w_dcn  = (const float*)d_in[3];
    const float* b_dcn  = (const float*)d_in[4];
    const float* gamma  = (const float*)d_in[5];
    const float* beta   = (const float*)d_in[6];
    const float* mmean  = (const float*)d_in[7];
    const float* mvar   = (const float*)d_in[8];
    float* out = (float*)d_out;

    char* ws = (char*)d_ws;
    u16* xtp   = (u16*)ws;                          // 8,388,608 B
    u16* wT    = (u16*)(ws + 8388608);              //   589,824 B
    u16* wOffT = (u16*)(ws + 8388608 + 589824);     //    73,728 B

    prep_xt  <<<dim3(HW/32, 2), 256, 0, stream>>>(x, xtp);
    prep_wall<<<dim3(9, 288), 128, 0, stream>>>(w_dcn, w_off, wT, wOffT);
    dcn_fused<<<dim3(PIX/64), 256, 0, stream>>>(xtp, wT, wOffT, b_off, b_dcn,
                                                gamma, beta, mmean, mvar, out);
}